// Round 2
// baseline (297.431 us; speedup 1.0000x reference)
//
#include <hip/hip_runtime.h>
#include <math.h>

#define DD 128
#define CF 48          // bucket capacity per row, full graph (Poisson λ=12, max deg ~30)
#define CP 48          // bucket capacity per row, pooled graph
#define OVF_CAP 4096   // overflow side-list capacity (expected use: 0 entries)

static inline int cdiv(long a, long b){ return (int)((a + b - 1) / b); }

typedef __attribute__((ext_vector_type(4))) float f32x4;
typedef __attribute__((ext_vector_type(8))) short bf16x8;
typedef __attribute__((ext_vector_type(4))) short sh4;

__device__ __forceinline__ unsigned short bf16_rn(float f){
  unsigned u = __float_as_uint(f);
  u += 0x7fffu + ((u >> 16) & 1u);
  return (unsigned short)(u >> 16);
}

// ---------- single-pass CSR-free build: count + direct bucket scatter (both graphs)
// + unpool inverse scatter. Replaces memset/count/bsum/scan_b/scan_f/fill (6 dispatches -> 1).
__global__ void k_scatter(const int* __restrict__ src_f, const int* __restrict__ dst_f, int Ef,
                          int* __restrict__ cnt_f, int* __restrict__ ewk_f,
                          int2* __restrict__ ovf_f, int* __restrict__ novf_f,
                          const int* __restrict__ src_p, const int* __restrict__ dst_p, int Ep,
                          int* __restrict__ cnt_p, int* __restrict__ ewk_p,
                          int2* __restrict__ ovf_p, int* __restrict__ novf_p,
                          const int* __restrict__ unpool, int* __restrict__ inv, int npool){
  int e = blockIdx.x * blockDim.x + threadIdx.x;
  if (e < Ef){
    int s = src_f[e], d = dst_f[e];
    int r = atomicAdd(&cnt_f[d], 1);
    if (r < CF) ewk_f[(long)d * CF + r] = s;
    else { int o = atomicAdd(novf_f, 1); if (o < OVF_CAP) ovf_f[o] = make_int2(s, d); }
    return;
  }
  e -= Ef;
  if (e < Ep){
    int s = src_p[e], d = dst_p[e];
    int r = atomicAdd(&cnt_p[d], 1);
    if (r < CP) ewk_p[(long)d * CP + r] = s;
    else { int o = atomicAdd(novf_p, 1); if (o < OVF_CAP) ovf_p[o] = make_int2(s, d); }
    return;
  }
  e -= Ep;
  if (e < npool) inv[unpool[e]] = e;
}

// ---------- MFMA GEMM: xw = A @ W, hi/lo bf16 split (fp32-grade accuracy)
// AMODE 0: A is fp32, split in-kernel. AMODE 1: A is packed ushort2{hi,lo} (uint per elem).
// 128 rows/block, 4 waves x 32 rows. W transposed+swizzled in LDS (hi/lo bf16, 64KB).
// D-layout (HW-verified): row = (lane>>4)*4 + reg, col = lane&15.
template <int AMODE, bool BF16OUT>
__global__ __launch_bounds__(256, 2) void k_gemm_mfma(const void* __restrict__ Ap,
                                                      const float* __restrict__ W,
                                                      void* __restrict__ Cout, int n){
  __shared__ unsigned short Wl[2][16384];   // [hi/lo][col-major bf16, XOR-swizzled 16B slots]
  const int t    = threadIdx.x;
  const int lane = t & 63;
  const int wv   = t >> 6;    // wave 0..3
  const int g    = lane >> 4; // k-group 0..3
  const int r    = lane & 15; // row-within-frag (A) / col-within-frag (B,D)

  // ---- stage W: read row-major fp32 coalesced, write transposed bf16 hi/lo ----
  // swizzle: byte = col*256 + ((k>>3) ^ (col&15))*16 + (k&7)*2
  #pragma unroll
  for (int i = 0; i < 4; i++){
    int item = t + i * 256;
    int kq = item >> 5;            // k = kq*4 + kk
    int c4 = item & 31;            // col = c4*4 + m
    const float* Wp = W + (long)kq * 512 + c4 * 4;
    float4 ww[4];
    #pragma unroll
    for (int kk = 0; kk < 4; kk++) ww[kk] = *(const float4*)(Wp + kk * 128);
    #pragma unroll
    for (int m = 0; m < 4; m++){
      int c = c4 * 4 + m;
      int boff = c * 256 + (((kq >> 1) ^ (c & 15)) * 16) + (kq & 1) * 8;
      sh4 hq, lq;
      #pragma unroll
      for (int kk = 0; kk < 4; kk++){
        float f = ((const float*)&ww[kk])[m];
        unsigned short hh = bf16_rn(f);
        float hf = __uint_as_float((unsigned)hh << 16);
        hq[kk] = (short)hh;
        lq[kk] = (short)bf16_rn(f - hf);
      }
      *(sh4*)((char*)(&Wl[0][0]) + boff) = hq;
      *(sh4*)((char*)(&Wl[1][0]) + boff) = lq;
    }
  }
  __syncthreads();

  const int rb = blockIdx.x * 128 + wv * 32;
  const int r0 = rb + r, r1 = rb + 16 + r;
  const bool v0 = r0 < n, v1 = r1 < n;

  f32x4 acc[2][8];
  #pragma unroll
  for (int i = 0; i < 2; i++)
    #pragma unroll
    for (int j = 0; j < 8; j++){ f32x4 z = {0.f,0.f,0.f,0.f}; acc[i][j] = z; }

  #pragma unroll
  for (int ks = 0; ks < 4; ks++){
    bf16x8 ah0, al0, ah1, al1;
    if (AMODE == 0){
      const float* pa0 = (const float*)Ap + (long)r0 * DD + g * 8;
      const float* pa1 = (const float*)Ap + (long)r1 * DD + g * 8;
      const float4 z4 = make_float4(0.f,0.f,0.f,0.f);
      float4 a00 = v0 ? *(const float4*)(pa0 + ks * 32)     : z4;
      float4 a01 = v0 ? *(const float4*)(pa0 + ks * 32 + 4) : z4;
      float4 a10 = v1 ? *(const float4*)(pa1 + ks * 32)     : z4;
      float4 a11 = v1 ? *(const float4*)(pa1 + ks * 32 + 4) : z4;
      float f0[8] = {a00.x,a00.y,a00.z,a00.w,a01.x,a01.y,a01.z,a01.w};
      float f1[8] = {a10.x,a10.y,a10.z,a10.w,a11.x,a11.y,a11.z,a11.w};
      #pragma unroll
      for (int i = 0; i < 8; i++){
        unsigned short hh = bf16_rn(f0[i]);
        ah0[i] = (short)hh;
        al0[i] = (short)bf16_rn(f0[i] - __uint_as_float((unsigned)hh << 16));
        unsigned short h1 = bf16_rn(f1[i]);
        ah1[i] = (short)h1;
        al1[i] = (short)bf16_rn(f1[i] - __uint_as_float((unsigned)h1 << 16));
      }
    } else {
      const unsigned* qa0 = (const unsigned*)Ap + (long)r0 * DD + g * 8;
      const unsigned* qa1 = (const unsigned*)Ap + (long)r1 * DD + g * 8;
      const uint4 z4 = make_uint4(0,0,0,0);
      uint4 u00 = v0 ? *(const uint4*)(qa0 + ks * 32)     : z4;
      uint4 u01 = v0 ? *(const uint4*)(qa0 + ks * 32 + 4) : z4;
      uint4 u10 = v1 ? *(const uint4*)(qa1 + ks * 32)     : z4;
      uint4 u11 = v1 ? *(const uint4*)(qa1 + ks * 32 + 4) : z4;
      unsigned uu0[8] = {u00.x,u00.y,u00.z,u00.w,u01.x,u01.y,u01.z,u01.w};
      unsigned uu1[8] = {u10.x,u10.y,u10.z,u10.w,u11.x,u11.y,u11.z,u11.w};
      #pragma unroll
      for (int i = 0; i < 8; i++){
        ah0[i] = (short)(uu0[i] & 0xffffu); al0[i] = (short)(uu0[i] >> 16);
        ah1[i] = (short)(uu1[i] & 0xffffu); al1[i] = (short)(uu1[i] >> 16);
      }
    }
    const int sb = ks * 4 + g;
    #pragma unroll
    for (int cf = 0; cf < 8; cf++){
      const int boff = (cf * 16 + r) * 256 + ((sb ^ r) * 16);
      bf16x8 wh = *(const bf16x8*)((const char*)(&Wl[0][0]) + boff);
      bf16x8 wl = *(const bf16x8*)((const char*)(&Wl[1][0]) + boff);
      acc[0][cf] = __builtin_amdgcn_mfma_f32_16x16x32_bf16(ah0, wh, acc[0][cf], 0, 0, 0);
      acc[1][cf] = __builtin_amdgcn_mfma_f32_16x16x32_bf16(ah1, wh, acc[1][cf], 0, 0, 0);
      acc[0][cf] = __builtin_amdgcn_mfma_f32_16x16x32_bf16(al0, wh, acc[0][cf], 0, 0, 0);
      acc[1][cf] = __builtin_amdgcn_mfma_f32_16x16x32_bf16(al1, wh, acc[1][cf], 0, 0, 0);
      acc[0][cf] = __builtin_amdgcn_mfma_f32_16x16x32_bf16(ah0, wl, acc[0][cf], 0, 0, 0);
      acc[1][cf] = __builtin_amdgcn_mfma_f32_16x16x32_bf16(ah1, wl, acc[1][cf], 0, 0, 0);
    }
  }

  #pragma unroll
  for (int rf = 0; rf < 2; rf++){
    #pragma unroll
    for (int cf = 0; cf < 8; cf++){
      #pragma unroll
      for (int e = 0; e < 4; e++){
        int row = rb + rf * 16 + g * 4 + e;
        if (row < n){
          float v = acc[rf][cf][e];
          if (BF16OUT)
            ((unsigned short*)Cout)[(long)row * DD + cf * 16 + r] = bf16_rn(v);
          else
            ((float*)Cout)[(long)row * DD + cf * 16 + r] = v;
        }
      }
    }
  }
}

// ---------- conv0 agg: pool graph, fp32 payload, packed hi/lo uint output ----------
__global__ __launch_bounds__(256) void k_agg0(const float* __restrict__ xw,
    const int* __restrict__ cnt, const int* __restrict__ ewk,
    const int2* __restrict__ ovf, const int* __restrict__ novf,
    const float* __restrict__ b, unsigned* __restrict__ outp, int n){
  int row = blockIdx.x * 4 + (threadIdx.x >> 6);
  if (row >= n) return;
  int c = (threadIdx.x & 63) * 2;
  int deg = __builtin_amdgcn_readfirstlane(cnt[row]);
  int m = deg < CP ? deg : CP;
  long base = (long)row * CP;
  float ax[4], ay[4];
  #pragma unroll
  for (int i = 0; i < 4; i++){ ax[i] = 0.f; ay[i] = 0.f; }
  int j = 0;
  for (; j + 3 < m; j += 4){
    int4 ss = *(const int4*)(ewk + base + j);
    int sa[4] = {ss.x, ss.y, ss.z, ss.w};
    #pragma unroll
    for (int i = 0; i < 4; i++){
      int s = sa[i];
      float w = rsqrtf((float)cnt[s] + 1.f);
      float2 v = *(const float2*)(xw + (long)s * DD + c);
      ax[i] += v.x * w; ay[i] += v.y * w;
    }
  }
  for (; j < m; j++){
    int s = ewk[base + j];
    float w = rsqrtf((float)cnt[s] + 1.f);
    float2 v = *(const float2*)(xw + (long)s * DD + c);
    ax[0] += v.x * w; ay[0] += v.y * w;
  }
  int no = __builtin_amdgcn_readfirstlane(novf[0]);
  if (no > 0){
    no = no < OVF_CAP ? no : OVF_CAP;
    for (int k = 0; k < no; k++){
      int2 od = ovf[k];
      if (od.y == row){
        float w = rsqrtf((float)cnt[od.x] + 1.f);
        float2 v = *(const float2*)(xw + (long)od.x * DD + c);
        ax[0] += v.x * w; ay[0] += v.y * w;
      }
    }
  }
  float sax = (ax[0]+ax[1]) + (ax[2]+ax[3]);
  float say = (ay[0]+ay[1]) + (ay[2]+ay[3]);
  float dd = rsqrtf((float)deg + 1.f);
  float2 sv = *(const float2*)(xw + (long)row * DD + c);
  float2 bb = *(const float2*)(b + c);
  float vx = sax * dd + sv.x * dd * dd + bb.x;
  float vy = say * dd + sv.y * dd * dd + bb.y;
  vx = vx > 0.f ? vx : expm1f(vx);
  vy = vy > 0.f ? vy : expm1f(vy);
  unsigned short hx = bf16_rn(vx);
  unsigned short lx = bf16_rn(vx - __uint_as_float((unsigned)hx << 16));
  unsigned short hy = bf16_rn(vy);
  unsigned short ly = bf16_rn(vy - __uint_as_float((unsigned)hy << 16));
  *(uint2*)(outp + (long)row * DD + c) =
      make_uint2((unsigned)hx | ((unsigned)lx << 16), (unsigned)hy | ((unsigned)ly << 16));
}

// ---------- conv1 agg: full graph, sparse bf16 payload, packed hi/lo uint output ----------
__global__ __launch_bounds__(256) void k_agg1(const unsigned short* __restrict__ hwb,
    const int* __restrict__ inv, const int* __restrict__ cnt,
    const int* __restrict__ ewk, const int2* __restrict__ ovf, const int* __restrict__ novf,
    const float* __restrict__ b, unsigned* __restrict__ outp, int n){
  int row = blockIdx.x * 4 + (threadIdx.x >> 6);
  if (row >= n) return;
  int c = (threadIdx.x & 63) * 2;
  int deg = __builtin_amdgcn_readfirstlane(cnt[row]);
  int m = deg < CF ? deg : CF;
  long base = (long)row * CF;
  float ax[8], ay[8];
  #pragma unroll
  for (int i = 0; i < 8; i++){ ax[i] = 0.f; ay[i] = 0.f; }
  int j = 0;
  for (; j + 7 < m; j += 8){
    int4 s0 = *(const int4*)(ewk + base + j);
    int4 s1 = *(const int4*)(ewk + base + j + 4);
    int sa[8] = {s0.x, s0.y, s0.z, s0.w, s1.x, s1.y, s1.z, s1.w};
    #pragma unroll
    for (int i = 0; i < 8; i++){
      int s = sa[i];
      int pr = inv[s];
      if (pr >= 0){
        float w = rsqrtf((float)cnt[s] + 1.f);
        unsigned v = *(const unsigned*)(hwb + (long)pr * DD + c);
        ax[i] += __uint_as_float(v << 16) * w;
        ay[i] += __uint_as_float(v & 0xffff0000u) * w;
      }
    }
  }
  for (; j < m; j++){
    int s = ewk[base + j];
    int pr = inv[s];
    if (pr >= 0){
      float w = rsqrtf((float)cnt[s] + 1.f);
      unsigned v = *(const unsigned*)(hwb + (long)pr * DD + c);
      ax[0] += __uint_as_float(v << 16) * w;
      ay[0] += __uint_as_float(v & 0xffff0000u) * w;
    }
  }
  int no = __builtin_amdgcn_readfirstlane(novf[0]);
  if (no > 0){
    no = no < OVF_CAP ? no : OVF_CAP;
    for (int k = 0; k < no; k++){
      int2 od = ovf[k];
      if (od.y == row){
        int pr = inv[od.x];
        if (pr >= 0){
          float w = rsqrtf((float)cnt[od.x] + 1.f);
          unsigned v = *(const unsigned*)(hwb + (long)pr * DD + c);
          ax[0] += __uint_as_float(v << 16) * w;
          ay[0] += __uint_as_float(v & 0xffff0000u) * w;
        }
      }
    }
  }
  float sax = ((ax[0]+ax[1])+(ax[2]+ax[3])) + ((ax[4]+ax[5])+(ax[6]+ax[7]));
  float say = ((ay[0]+ay[1])+(ay[2]+ay[3])) + ((ay[4]+ay[5])+(ay[6]+ay[7]));
  float dd = rsqrtf((float)deg + 1.f);
  int pr = inv[row];
  float sx = 0.f, sy = 0.f;
  if (pr >= 0){
    unsigned sv = *(const unsigned*)(hwb + (long)pr * DD + c);
    sx = __uint_as_float(sv << 16); sy = __uint_as_float(sv & 0xffff0000u);
  }
  float2 bb = *(const float2*)(b + c);
  float vx = sax * dd + sx * dd * dd + bb.x;
  float vy = say * dd + sy * dd * dd + bb.y;
  vx = vx > 0.f ? vx : expm1f(vx);
  vy = vy > 0.f ? vy : expm1f(vy);
  unsigned short hx = bf16_rn(vx);
  unsigned short lx = bf16_rn(vx - __uint_as_float((unsigned)hx << 16));
  unsigned short hy = bf16_rn(vy);
  unsigned short ly = bf16_rn(vy - __uint_as_float((unsigned)hy << 16));
  *(uint2*)(outp + (long)row * DD + c) =
      make_uint2((unsigned)hx | ((unsigned)lx << 16), (unsigned)hy | ((unsigned)ly << 16));
}

// ---------- conv2 agg: full graph, bf16 payload, fp32 output (final) ----------
__global__ __launch_bounds__(256) void k_agg2(const unsigned short* __restrict__ xwb,
    const int* __restrict__ cnt, const int* __restrict__ ewk,
    const int2* __restrict__ ovf, const int* __restrict__ novf,
    const float* __restrict__ b, float* __restrict__ out, int n){
  int row = blockIdx.x * 4 + (threadIdx.x >> 6);
  if (row >= n) return;
  int c = (threadIdx.x & 63) * 2;
  int deg = __builtin_amdgcn_readfirstlane(cnt[row]);
  int m = deg < CF ? deg : CF;
  long base = (long)row * CF;
  float ax[8], ay[8];
  #pragma unroll
  for (int i = 0; i < 8; i++){ ax[i] = 0.f; ay[i] = 0.f; }
  int j = 0;
  for (; j + 7 < m; j += 8){
    int4 s0 = *(const int4*)(ewk + base + j);
    int4 s1 = *(const int4*)(ewk + base + j + 4);
    int sa[8] = {s0.x, s0.y, s0.z, s0.w, s1.x, s1.y, s1.z, s1.w};
    #pragma unroll
    for (int i = 0; i < 8; i++){
      int s = sa[i];
      float w = rsqrtf((float)cnt[s] + 1.f);
      unsigned v = *(const unsigned*)(xwb + (long)s * DD + c);
      ax[i] += __uint_as_float(v << 16) * w;
      ay[i] += __uint_as_float(v & 0xffff0000u) * w;
    }
  }
  for (; j < m; j++){
    int s = ewk[base + j];
    float w = rsqrtf((float)cnt[s] + 1.f);
    unsigned v = *(const unsigned*)(xwb + (long)s * DD + c);
    ax[0] += __uint_as_float(v << 16) * w;
    ay[0] += __uint_as_float(v & 0xffff0000u) * w;
  }
  int no = __builtin_amdgcn_readfirstlane(novf[0]);
  if (no > 0){
    no = no < OVF_CAP ? no : OVF_CAP;
    for (int k = 0; k < no; k++){
      int2 od = ovf[k];
      if (od.y == row){
        float w = rsqrtf((float)cnt[od.x] + 1.f);
        unsigned v = *(const unsigned*)(xwb + (long)od.x * DD + c);
        ax[0] += __uint_as_float(v << 16) * w;
        ay[0] += __uint_as_float(v & 0xffff0000u) * w;
      }
    }
  }
  float sax = ((ax[0]+ax[1])+(ax[2]+ax[3])) + ((ax[4]+ax[5])+(ax[6]+ax[7]));
  float say = ((ay[0]+ay[1])+(ay[2]+ay[3])) + ((ay[4]+ay[5])+(ay[6]+ay[7]));
  float dd = rsqrtf((float)deg + 1.f);
  unsigned sv = *(const unsigned*)(xwb + (long)row * DD + c);
  float sx = __uint_as_float(sv << 16), sy = __uint_as_float(sv & 0xffff0000u);
  float2 bb = *(const float2*)(b + c);
  float vx = sax * dd + sx * dd * dd + bb.x;
  float vy = say * dd + sy * dd * dd + bb.y;
  vx = vx > 0.f ? vx : expm1f(vx);
  vy = vy > 0.f ? vy : expm1f(vy);
  *(float2*)(out + (long)row * DD + c) = make_float2(vx, vy);
}

extern "C" void kernel_launch(void* const* d_in, const int* in_sizes, int n_in,
                              void* d_out, int out_size, void* d_ws, size_t ws_size,
                              hipStream_t stream) {
  const int*   edge   = (const int*)d_in[1];
  const float* px     = (const float*)d_in[2];
  const int*   pedge  = (const int*)d_in[3];
  const int*   unpool = (const int*)d_in[4];
  const float* W0 = (const float*)d_in[5]; const float* b0 = (const float*)d_in[6];
  const float* W1 = (const float*)d_in[7]; const float* b1 = (const float*)d_in[8];
  const float* W2 = (const float*)d_in[9]; const float* b2 = (const float*)d_in[10];
  const int n_full = in_sizes[0] / DD;
  const int E_full = in_sizes[1] / 2;
  const int n_pool = in_sizes[2] / DD;
  const int E_pool = in_sizes[3] / 2;
  float* out = (float*)d_out;

  // ---- workspace layout ----
  char* w = (char*)d_ws;
  size_t off = 0;
  auto alloc = [&](size_t bytes) -> void* {
    void* p = (void*)(w + off);
    off += (bytes + 255) / 256 * 256;
    return p;
  };
  // zeroed span: [cnt_p | cnt_f | novf2]
  int* cnt_p  = (int*)alloc((size_t)n_pool * 4);
  int* cnt_f  = (int*)alloc((size_t)n_full * 4);
  int* novf2  = (int*)alloc(8);                       // [0]=pool ovf count, [1]=full ovf count
  size_t zspan = (size_t)((char*)(novf2 + 2) - (char*)cnt_p);
  int* invm   = (int*)alloc((size_t)n_full * 4);      // memset 0xFF -> -1
  int* ewk_p  = (int*)alloc((size_t)n_pool * CP * 4); // bucketed src ids
  int* ewk_f  = (int*)alloc((size_t)n_full * CF * 4);
  int2* ovf_p = (int2*)alloc((size_t)OVF_CAP * 8);
  int2* ovf_f = (int2*)alloc((size_t)OVF_CAP * 8);
  const size_t big = (size_t)n_full * DD * 4;
  float* bufA = (float*)alloc(big);
  float* bufB = (float*)alloc(big);

  const int* src_f = edge;          const int* dst_f = edge + E_full;
  const int* src_p = pedge;         const int* dst_p = pedge + E_pool;

  (void)hipMemsetAsync(cnt_p, 0, zspan, stream);
  (void)hipMemsetAsync(invm, 0xFF, (size_t)n_full * 4, stream);
  k_scatter<<<cdiv((long)E_full + E_pool + n_pool, 256), 256, 0, stream>>>(
      src_f, dst_f, E_full, cnt_f, ewk_f, ovf_f, novf2 + 1,
      src_p, dst_p, E_pool, cnt_p, ewk_p, ovf_p, novf2 + 0,
      unpool, invm, n_pool);

  float* xw0            = bufA;                   // pool rows fp32
  unsigned* h0p         = (unsigned*)bufB;        // pool rows packed hi/lo
  unsigned short* hw1b  = (unsigned short*)bufA;  // pool rows bf16 (xw0 dead)
  unsigned* y1p         = (unsigned*)bufB;        // full rows packed hi/lo (h0p dead after gemm1)
  unsigned short* xw2b  = (unsigned short*)bufA;  // full rows bf16 (hw1b dead after agg1)

  // conv0 (pooled graph)
  k_gemm_mfma<0,false><<<cdiv(n_pool,128),256,0,stream>>>(px, W0, xw0, n_pool);
  k_agg0<<<cdiv(n_pool,4),256,0,stream>>>(xw0, cnt_p, ewk_p, ovf_p, novf2 + 0, b0, h0p, n_pool);

  // conv1 (full graph, sparse bf16 payload)
  k_gemm_mfma<1,true><<<cdiv(n_pool,128),256,0,stream>>>(h0p, W1, hw1b, n_pool);
  k_agg1<<<cdiv(n_full,4),256,0,stream>>>(hw1b, invm, cnt_f, ewk_f, ovf_f, novf2 + 1, b1, y1p, n_full);

  // conv2 (full graph, bf16 gather payload)
  k_gemm_mfma<1,true><<<cdiv(n_full,128),256,0,stream>>>(y1p, W2, xw2b, n_full);
  k_agg2<<<cdiv(n_full,4),256,0,stream>>>(xw2b, cnt_f, ewk_f, ovf_f, novf2 + 1, b2, out, n_full);
}